// Round 1
// baseline (7956.066 us; speedup 1.0000x reference)
//
#include <hip/hip_runtime.h>

typedef unsigned short u16;
typedef unsigned int u32;
typedef __attribute__((ext_vector_type(4))) float f32x4;
typedef __attribute__((ext_vector_type(8))) short s16x8;

#define B_ 64
#define T_ 512
#define E_ 1024
#define H_ 1024
#define HE_ 2048
#define N4_ 4096   // 4*H
#define NWG_ 64

__device__ __forceinline__ u16 f32_bf16(float f) {
  union { float f; u32 u; } v; v.f = f;
  u32 r = v.u + 0x7FFFu + ((v.u >> 16) & 1u);
  return (u16)(r >> 16);
}
__device__ __forceinline__ float bf16_f32(u16 h) {
  union { u32 u; float f; } v; v.u = ((u32)h) << 16;
  return v.f;
}
__device__ __forceinline__ void async16(void* lds, const void* g) {
  __builtin_amdgcn_global_load_lds(
      (const __attribute__((address_space(1))) void*)g,
      (__attribute__((address_space(3))) void*)lds, 16, 0, 0);
}
__device__ __forceinline__ float sigmoidf_(float x) {
  return 1.0f / (1.0f + __expf(-x));
}

// ---------------- fp32 -> bf16 bulk convert (4 elems/thread) ----------------
__global__ __launch_bounds__(256) void cvt4(const float* __restrict__ s,
                                            u16* __restrict__ d, int n4) {
  int i = blockIdx.x * 256 + threadIdx.x;
  if (i < n4) {
    float4 v = ((const float4*)s)[i];
    u16 o0 = f32_bf16(v.x), o1 = f32_bf16(v.y), o2 = f32_bf16(v.z), o3 = f32_bf16(v.w);
    ushort4 o; o.x = o0; o.y = o1; o.z = o2; o.w = o3;
    ((ushort4*)d)[i] = o;
  }
}

// ---------------- init: a0->bf16, bias concat, barrier reset ----------------
__global__ __launch_bounds__(256) void init_k(const float* __restrict__ a0,
                                              const float* __restrict__ bc,
                                              const float* __restrict__ bu,
                                              const float* __restrict__ bf_,
                                              const float* __restrict__ bo,
                                              u16* __restrict__ abuf0,
                                              float* __restrict__ bias4,
                                              int* __restrict__ bar) {
  int i = blockIdx.x * 256 + threadIdx.x;   // 65536 threads
  abuf0[i] = f32_bf16(a0[i]);
  if (i < N4_) {
    int g = i >> 10, h = i & 1023;
    const float* bp = (g == 0) ? bc : (g == 1) ? bu : (g == 2) ? bf_ : bo;
    bias4[i] = bp[h];
  }
  if (i < T_) bar[i] = 0;   // re-zero every graph replay
}

// ---------------- phase 1: P[t][b][n] = bf16( X @ WxT + bias ) ----------------
// (unchanged from verified baseline)
__global__ __launch_bounds__(256) void gemm_p1(const u16* __restrict__ Xbf,
                                               const u16* __restrict__ Wbf,
                                               const float* __restrict__ bias4,
                                               u16* __restrict__ P) {
  __shared__ __align__(16) u16 As[128 * 64];
  __shared__ __align__(16) u16 Bs[128 * 64];
  int tid = threadIdx.x;
  int wid = tid >> 6, lane = tid & 63;
  int lane15 = lane & 15, quad = lane >> 4;
  int m0 = blockIdx.y * 128, n0 = blockIdx.x * 128;
  int wm = (wid >> 1) * 64, wn = (wid & 1) * 64;

  f32x4 acc[4][4] = {};

  for (int kc = 0; kc < 1024; kc += 64) {
    __syncthreads();
    for (int i = 0; i < 8; ++i) {
      int c = wid * 8 + i;
      int o = c * 1024 + lane * 16;
      int e = (o & 16383) >> 1;
      int row = e >> 6, kcol = e & 63;
      if (o < 16384) {
        async16((char*)As + c * 1024,
                Xbf + (size_t)(m0 + row) * 1024 + kc + kcol);
      } else {
        async16((char*)Bs + (c - 16) * 1024,
                Wbf + (size_t)(n0 + row) * 2048 + 1024 + kc + kcol);
      }
    }
    __syncthreads();
    for (int s = 0; s < 2; ++s) {
      s16x8 bfrag[4], afrag[4];
      for (int ni = 0; ni < 4; ++ni)
        bfrag[ni] = *(const s16x8*)&Bs[(wn + ni * 16 + lane15) * 64 + s * 32 + quad * 8];
      for (int mi = 0; mi < 4; ++mi)
        afrag[mi] = *(const s16x8*)&As[(wm + mi * 16 + lane15) * 64 + s * 32 + quad * 8];
      for (int mi = 0; mi < 4; ++mi)
        for (int ni = 0; ni < 4; ++ni)
          acc[mi][ni] = __builtin_amdgcn_mfma_f32_16x16x32_bf16(
              afrag[mi], bfrag[ni], acc[mi][ni], 0, 0, 0);
    }
  }
  for (int mi = 0; mi < 4; ++mi) {
    int mbase = m0 + wm + mi * 16 + quad * 4;
    for (int ni = 0; ni < 4; ++ni) {
      int n = n0 + wn + ni * 16 + lane15;
      float bv = bias4[n];
      for (int r = 0; r < 4; ++r) {
        int m = mbase + r;
        int b = m >> 9, t = m & 511;
        float v = acc[mi][ni][r] + bv;
        P[(size_t)(t * 64 + b) * N4_ + n] = f32_bf16(v);
      }
    }
  }
}

// ---------------- phase 2: PERSISTENT scan kernel ----------------
// 64 WGs x 256 threads, 1 WG/CU. WG hb owns h-slice [hb*16, hb*16+16) of all
// 4 gates for all 512 steps.
//   - W slice (4 gates x 16 rows x 1024 k bf16 = 128KB) lives in LDS, swizzled,
//     loaded ONCE  -> zero per-step W traffic (vs 8MB/step re-fetch after the
//     per-launch L2 invalidation in the old 512-launch version).
//   - c state in registers.
//   - a_prev staged in 16 BK=64 chunks, 4 LDS buffers, depth-2 prefetch with
//     counted vmcnt(4) + raw s_barrier (loads stay in flight across barriers).
//   - steps separated by a device-scope atomic grid barrier (64 co-resident WGs).
__global__ __launch_bounds__(256) void scan_k(const u16* __restrict__ Wbf,
                                              const u16* __restrict__ P,
                                              const float* __restrict__ c0,
                                              u16* __restrict__ ab0,
                                              u16* __restrict__ ab1,
                                              float* __restrict__ a_out,
                                              float* __restrict__ out_aT,
                                              float* __restrict__ out_cT,
                                              int* __restrict__ bar) {
  // LDS map: [0,131072) W swizzled | [131072,163840) 4x8KB a-chunk bufs
  //          act (f32 [256][17] = 17408B) overlaps bufs 0..2 (used only after K-loop)
  __shared__ __align__(16) char smem[163840];
  float* act = (float*)(smem + 131072);

  const int tid = threadIdx.x;
  const int g = tid >> 6, lane = tid & 63;      // wave g = gate g
  const int lane15 = lane & 15, quad = lane >> 4;
  const int h0 = blockIdx.x * 16;

  // ---- W slice -> LDS (XOR-swizzled: byte ^= (row&7)<<4), once ----
  for (int it = 0; it < 32; ++it) {
    int j = it * 256 + tid;                     // 16B chunk index, 8192 total
    int o = j * 16;
    int grow = o >> 11, kb = o & 2047;          // row (g*16+nl), byte in row
    s16x8 v = *(const s16x8*)(Wbf +
        (size_t)((grow >> 4) * 1024 + h0 + (grow & 15)) * 2048 + (kb >> 1));
    *(s16x8*)(smem + ((grow << 11) | (kb ^ ((grow & 7) << 4)))) = v;
  }

  // ---- c0 -> registers ----
  float c_reg[4];
#pragma unroll
  for (int j = 0; j < 4; ++j) {
    int e = j * 256 + tid;                      // b*16 + hh
    c_reg[j] = c0[(e >> 4) * 1024 + h0 + (e & 15)];
  }

  // per-thread pre-swizzled global source offsets for a-staging (bytes):
  // LDS linear dst byte o gets global a byte  row*2048 + ((o&127) ^ (row&7)<<4)
  int soff[2];
#pragma unroll
  for (int i = 0; i < 2; ++i) {
    int o = (g * 2 + i) * 1024 + lane * 16;
    int row = o >> 7, x = o & 127;
    soff[i] = row * 2048 + (x ^ ((row & 7) << 4));
  }

  // ---- P prefetch for t=0 (bias already folded in by phase 1) ----
  u16 pc[16];
  {
    const u16* Pt = P + g * 1024 + h0 + lane15;
#pragma unroll
    for (int q = 0; q < 16; ++q)
      pc[q] = Pt[(size_t)((q >> 2) * 16 + quad * 4 + (q & 3)) * N4_];
  }
  __syncthreads();   // W in LDS visible to all waves

#define STAGE(bufidx, kc)                                                      \
  {                                                                            \
    char* bb = smem + 131072 + (bufidx) * 8192;                                \
    async16(bb + (g * 2 + 0) * 1024, (const char*)ap + soff[0] + (kc) * 2);    \
    async16(bb + (g * 2 + 1) * 1024, (const char*)ap + soff[1] + (kc) * 2);    \
  }

#define KCHUNK(bufidx, kc)                                                     \
  _Pragma("unroll") for (int s = 0; s < 2; ++s) {                              \
    const int wrow = g * 16 + lane15;                                          \
    s16x8 bfrag = *(const s16x8*)(smem + ((wrow << 11) |                       \
        ((((kc) + s * 32 + quad * 8) * 2) ^ ((wrow & 7) << 4))));              \
    _Pragma("unroll") for (int mi = 0; mi < 4; ++mi) {                         \
      const int arow = mi * 16 + lane15;                                       \
      s16x8 afrag = *(const s16x8*)(smem + 131072 + (bufidx) * 8192 +          \
          ((arow << 7) | ((s * 64 + quad * 16) ^ ((arow & 7) << 4))));         \
      acc[mi] = __builtin_amdgcn_mfma_f32_16x16x32_bf16(afrag, bfrag,          \
                                                        acc[mi], 0, 0, 0);     \
    }                                                                          \
  }

#pragma unroll 1
  for (int t = 0; t < T_; ++t) {
    const u16* ap = (t & 1) ? ab1 : ab0;
    u16* an = (t & 1) ? ab0 : ab1;

    f32x4 acc[4] = {};

    // K-loop: BK=64, 16 chunks, depth-2 prefetch, counted vmcnt, raw barriers.
    STAGE(0, 0);
    STAGE(1, 64);
#pragma unroll
    for (int c = 0; c < 16; ++c) {
      if (c < 14) {
        STAGE((c + 2) & 3, (c + 2) * 64);
        // queue per wave: [s_c(2), s_{c+1}(2), s_{c+2}(2)] -> wait s_c done
        asm volatile("s_waitcnt vmcnt(4)\n\ts_barrier" ::: "memory");
      } else if (c == 14) {
        asm volatile("s_waitcnt vmcnt(2)\n\ts_barrier" ::: "memory");
      } else {
        asm volatile("s_waitcnt vmcnt(0)\n\ts_barrier" ::: "memory");
      }
      KCHUNK(c & 3, c * 64);
    }

    // ---- gate activations -> act LDS (stride 17 kills the 4-way conflict) ----
    // (act overlaps bufs 0..2; last KCHUNK reads buf 3, so no clash)
#pragma unroll
    for (int mi = 0; mi < 4; ++mi)
#pragma unroll
      for (int r = 0; r < 4; ++r) {
        int b = mi * 16 + quad * 4 + r;
        float v = acc[mi][r] + bf16_f32(pc[mi * 4 + r]);
        v = (g == 0) ? tanhf(v) : sigmoidf_(v);
        act[(b * 4 + g) * 17 + lane15] = v;
      }
    __syncthreads();

    // ---- elementwise state update + outputs ----
#pragma unroll
    for (int j = 0; j < 4; ++j) {
      int e = j * 256 + tid;
      int b = e >> 4, hh = e & 15;
      float cand = act[(b * 4 + 0) * 17 + hh];
      float uu   = act[(b * 4 + 1) * 17 + hh];
      float ff   = act[(b * 4 + 2) * 17 + hh];
      float oo   = act[(b * 4 + 3) * 17 + hh];
      float c1 = uu * cand + ff * c_reg[j];
      c_reg[j] = c1;
      float a1 = oo * tanhf(c1);
      a_out[((size_t)b * T_ + t) * H_ + h0 + hh] = a1;
      an[b * 1024 + h0 + hh] = f32_bf16(a1);
      if (t == T_ - 1) {
        out_aT[b * 1024 + h0 + hh] = a1;
        out_cT[b * 1024 + h0 + hh] = c1;
      }
    }

    // ---- device-scope grid barrier (skip after last step) ----
    if (t < T_ - 1) {
      __builtin_amdgcn_fence(__ATOMIC_RELEASE, "agent");  // flush a_next to L3
      __syncthreads();
      // P prefetch for t+1 overlaps the barrier spin
      u16 pn[16];
      {
        const u16* Pt = P + (size_t)(t + 1) * 64 * N4_ + g * 1024 + h0 + lane15;
#pragma unroll
        for (int q = 0; q < 16; ++q)
          pn[q] = Pt[(size_t)((q >> 2) * 16 + quad * 4 + (q & 3)) * N4_];
      }
      if (tid == 0) {
        atomicAdd(&bar[t], 1);
        while (__hip_atomic_load(&bar[t], __ATOMIC_RELAXED,
                                 __HIP_MEMORY_SCOPE_AGENT) < NWG_)
          __builtin_amdgcn_s_sleep(1);
      }
      __syncthreads();
      __builtin_amdgcn_fence(__ATOMIC_ACQUIRE, "agent");  // invalidate stale L2
#pragma unroll
      for (int q = 0; q < 16; ++q) pc[q] = pn[q];
    }
  }
#undef STAGE
#undef KCHUNK
}

extern "C" void kernel_launch(void* const* d_in, const int* in_sizes, int n_in,
                              void* d_out, int out_size, void* d_ws, size_t ws_size,
                              hipStream_t stream) {
  const float* x_i = (const float*)d_in[0];
  const float* a0  = (const float*)d_in[1];
  const float* c0  = (const float*)d_in[2];
  const float* w[4] = {(const float*)d_in[3], (const float*)d_in[4],
                       (const float*)d_in[5], (const float*)d_in[6]};
  const float* bb[4] = {(const float*)d_in[7], (const float*)d_in[8],
                        (const float*)d_in[9], (const float*)d_in[10]};
  float* out = (float*)d_out;

  char* ws = (char*)d_ws;
  u16* Wbf   = (u16*)ws;                          // 16,777,216 B
  u16* Xbf   = (u16*)(ws + 16777216);             // 67,108,864 B
  u16* P     = (u16*)(ws + 83886080);             // 268,435,456 B
  float* bias4 = (float*)(ws + 352321536);        // 16,384 B
  u16* abuf0 = (u16*)(ws + 352337920);            // 131,072 B
  u16* abuf1 = (u16*)(ws + 352468992);            // 131,072 B
  int* bar   = (int*)(ws + 352600064);            // 2,048 B

  for (int g = 0; g < 4; ++g)
    cvt4<<<2048, 256, 0, stream>>>(w[g], Wbf + (size_t)g * 1024 * 2048, 524288);
  cvt4<<<32768, 256, 0, stream>>>(x_i, Xbf, 8388608);
  init_k<<<256, 256, 0, stream>>>(a0, bb[0], bb[1], bb[2], bb[3],
                                  abuf0, bias4, bar);
  gemm_p1<<<dim3(32, 256), 256, 0, stream>>>(Xbf, Wbf, bias4, P);
  // phase 2: single persistent kernel replaces 512 step_k launches
  scan_k<<<64, 256, 0, stream>>>(Wbf, P, c0, abuf0, abuf1,
                                 out, out + 33554432, out + 33619968, bar);
}